// Round 15
// baseline (769.923 us; speedup 1.0000x reference)
//
#include <hip/hip_runtime.h>
#include <hip/hip_bf16.h>
#include <math.h>

#define L_TOK 5440
#define NTOK  10880   // B * L
#define D     256

typedef __attribute__((ext_vector_type(8))) short short8;
typedef __attribute__((ext_vector_type(4))) short short4v;
typedef __attribute__((ext_vector_type(4))) float f32x4;
typedef __attribute__((ext_vector_type(2))) float v2f;
typedef __attribute__((ext_vector_type(4))) int int4v;

__device__ __forceinline__ short f2bf(float f) {
    __hip_bfloat16 h = __float2bfloat16(f);
    return __builtin_bit_cast(short, h);
}
__device__ __forceinline__ float bf2f(short s) {
    unsigned u = ((unsigned)(unsigned short)s) << 16;
    return __builtin_bit_cast(float, u);
}

#define GLL16(gp, lp) \
    __builtin_amdgcn_global_load_lds((const __attribute__((address_space(1))) void*)(gp), \
                                     (__attribute__((address_space(3))) void*)(lp), 16, 0, 0)

// counted vmcnt wait + scheduler fence (rule #18: hipcc may hoist MFMA past inline-asm waits)
template<int N> __device__ __forceinline__ void waitcnt_vm() {
    if constexpr (N == 0)       asm volatile("s_waitcnt vmcnt(0)" ::: "memory");
    else if constexpr (N == 4)  asm volatile("s_waitcnt vmcnt(4)" ::: "memory");
    else if constexpr (N == 6)  asm volatile("s_waitcnt vmcnt(6)" ::: "memory");
    else if constexpr (N == 8)  asm volatile("s_waitcnt vmcnt(8)" ::: "memory");
    else if constexpr (N == 12) asm volatile("s_waitcnt vmcnt(12)" ::: "memory");
    __builtin_amdgcn_sched_barrier(0);
}

// ---------------- flatten (single launch): (B,d,H,W) -> (B,L,d) f32 + bf16, pos += level_embed
__global__ __launch_bounds__(256) void flat_all(
    const float* __restrict__ s0, const float* __restrict__ p0,
    const float* __restrict__ s1, const float* __restrict__ p1,
    const float* __restrict__ s2, const float* __restrict__ p2,
    const float* __restrict__ s3, const float* __restrict__ p3,
    const float* __restrict__ le,
    float* __restrict__ x, short* __restrict__ xb, float* __restrict__ pos)
{
    __shared__ float ts[32][33], tp[32][33];
    int idx = blockIdx.x;
    const float *s, *p; int HW, start, lv, xt;
    if (idx < 2048)      {             s = s0; p = p0; HW = 4096; start = 0;    lv = 0; xt = 128; }
    else if (idx < 2560) { idx -= 2048; s = s1; p = p1; HW = 1024; start = 4096; lv = 1; xt = 32; }
    else if (idx < 2688) { idx -= 2560; s = s2; p = p2; HW = 256;  start = 5120; lv = 2; xt = 8; }
    else                 { idx -= 2688; s = s3; p = p3; HW = 64;   start = 5376; lv = 3; xt = 2; }
    int pix0 = (idx % xt) * 32;
    int rem  = idx / xt;
    int c0   = (rem & 7) * 32;
    int b    = rem >> 3;
    int tx = threadIdx.x & 31, ty = threadIdx.x >> 5;
#pragma unroll
    for (int i = 0; i < 4; ++i) {
        int c = c0 + ty + i * 8;
        size_t gi = ((size_t)b * D + c) * HW + pix0 + tx;
        ts[ty + i * 8][tx] = s[gi];
        tp[ty + i * 8][tx] = p[gi];
    }
    __syncthreads();
#pragma unroll
    for (int i = 0; i < 4; ++i) {
        int pix = pix0 + ty + i * 8;
        size_t bl = (size_t)b * L_TOK + start + pix;
        int c = c0 + tx;
        float v = ts[tx][ty + i * 8];
        x[bl * D + c]   = v;
        xb[bl * D + c]  = f2bf(v);
        pos[bl * D + c] = tp[tx][ty + i * 8] + le[lv * D + c];
    }
}

// ---------------- weight convert+transpose + bias pack, ALL in one launch ----------------
__global__ __launch_bounds__(256) void wconv_all(
    const float* __restrict__ Woff, const float* __restrict__ Watt,
    const float* __restrict__ Wval, const float* __restrict__ Wout,
    const float* __restrict__ W1,   const float* __restrict__ W2,
    const float* __restrict__ boff, const float* __restrict__ batt,
    short* __restrict__ wt_qa, short* __restrict__ wt_val, short* __restrict__ wt_out,
    short* __restrict__ wt_1,  short* __restrict__ wt_2, float* __restrict__ bqa)
{
    __shared__ float tile[32][33];
    int tidx = blockIdx.x, d = blockIdx.z;
    if (tidx == 832) {
        for (int c = threadIdx.x; c < 768; c += 256)
            bqa[d * 768 + c] = (c < 512) ? boff[d * 512 + c] : batt[d * 256 + c - 512];
        return;
    }
    const float* W; short* Wt; int K, N, dstride, rowoff, nx, t;
    if (tidx < 128)      { W = Woff; Wt = wt_qa;  K = 256;  N = 512;  dstride = 768 * 256;  rowoff = 0;   nx = 16; t = tidx; }
    else if (tidx < 192) { W = Watt; Wt = wt_qa;  K = 256;  N = 256;  dstride = 768 * 256;  rowoff = 512; nx = 8;  t = tidx - 128; }
    else if (tidx < 256) { W = Wval; Wt = wt_val; K = 256;  N = 256;  dstride = 256 * 256;  rowoff = 0;   nx = 8;  t = tidx - 192; }
    else if (tidx < 320) { W = Wout; Wt = wt_out; K = 256;  N = 256;  dstride = 256 * 256;  rowoff = 0;   nx = 8;  t = tidx - 256; }
    else if (tidx < 576) { W = W1;   Wt = wt_1;   K = 256;  N = 1024; dstride = 1024 * 256; rowoff = 0;   nx = 32; t = tidx - 320; }
    else                 { W = W2;   Wt = wt_2;   K = 1024; N = 256;  dstride = 256 * 1024; rowoff = 0;   nx = 8;  t = tidx - 576; }
    int n0 = (t % nx) * 32, k0 = (t / nx) * 32;
    const float* Wd = W + (size_t)d * K * N;
    short* Wtd = Wt + (size_t)d * dstride + (size_t)rowoff * K;
    int tx = threadIdx.x & 31, ty = threadIdx.x >> 5;
#pragma unroll
    for (int i = 0; i < 4; ++i)
        tile[ty + i * 8][tx] = Wd[(size_t)(k0 + ty + i * 8) * N + n0 + tx];
    __syncthreads();
#pragma unroll
    for (int i = 0; i < 4; ++i)
        Wtd[(size_t)(n0 + ty + i * 8) * K + k0 + tx] = f2bf(tile[tx][ty + i * 8]);
}

// ---------------- LayerNorm -> bf16 (one wave per token, float4 vectorized) ----------------
__global__ __launch_bounds__(256) void ln_kernel(
    const float* __restrict__ x, const float* __restrict__ g, const float* __restrict__ bta,
    const float* __restrict__ pos, short* __restrict__ out)
{
    int wid = threadIdx.x >> 6, lane = threadIdx.x & 63;
    int m = blockIdx.x * 4 + wid;
    int c4 = lane * 4;
    const float4 xv = *(const float4*)&x[(size_t)m * D + c4];
    float s = xv.x + xv.y + xv.z + xv.w;
#pragma unroll
    for (int o = 32; o; o >>= 1) s += __shfl_xor(s, o);
    float mean = s * (1.0f / D);
    float d0 = xv.x - mean, d1 = xv.y - mean, d2 = xv.z - mean, d3 = xv.w - mean;
    float sq = d0 * d0 + d1 * d1 + d2 * d2 + d3 * d3;
#pragma unroll
    for (int o = 32; o; o >>= 1) sq += __shfl_xor(sq, o);
    float rstd = rsqrtf(sq * (1.0f / D) + 1e-5f);
    const float4 gv = *(const float4*)&g[c4];
    const float4 bv = *(const float4*)&bta[c4];
    float o0 = d0 * rstd * gv.x + bv.x;
    float o1 = d1 * rstd * gv.y + bv.y;
    float o2 = d2 * rstd * gv.z + bv.z;
    float o3 = d3 * rstd * gv.w + bv.w;
    if (pos) {
        const float4 pv = *(const float4*)&pos[(size_t)m * D + c4];
        o0 += pv.x; o1 += pv.y; o2 += pv.z; o3 += pv.w;
    }
    short4v ov;
    ov[0] = f2bf(o0); ov[1] = f2bf(o1); ov[2] = f2bf(o2); ov[3] = f2bf(o3);
    *(short4v*)&out[(size_t)m * D + c4] = ov;
}

// ---------------- bf16 MFMA GEMM body (BM=64 x BN, BK=64, 4 waves) ----------------
// DEPTH-3 pipeline (T3/T4): 3 LDS buffers; stage issued 2 K-steps ahead; counted
// s_waitcnt vmcnt(2*LPW / LPW / 0) + sched_barrier(0) + raw s_barrier — loads stay
// in flight across barriers instead of the __syncthreads vmcnt(0) drain.
template<int BN>
__device__ __forceinline__ void mm_body64(
    const short* __restrict__ A, const short* __restrict__ Wt,
    const float* __restrict__ bias, const float* __restrict__ resid,
    float* __restrict__ Cf, short* __restrict__ Cb,
    int row0, int col0, int K, int ldc, int act, int f16out)
{
    constexpr int NW  = BN / 4;
    constexpr int NF  = NW / 16;
    constexpr int BCH = BN / 32;
    constexpr int LPW = 2 + BCH;          // global_load_lds per wave per stage
    __shared__ __align__(16) short As[3][64 * 64];
    __shared__ __align__(16) short Bs[3][BN * 64];
    int tid = threadIdx.x, lane = tid & 63, w = tid >> 6;
    int l15 = lane & 15, l16 = lane >> 4;

    int a_off[4][2], b_off[NF][2];
#pragma unroll
    for (int m = 0; m < 4; ++m)
#pragma unroll
        for (int kk = 0; kk < 2; ++kk) {
            int ra = m * 16 + l15;
            a_off[m][kk] = ra * 64 + (((kk * 4 + l16) ^ (ra & 7)) << 3);
        }
#pragma unroll
    for (int n = 0; n < NF; ++n)
#pragma unroll
        for (int kk = 0; kk < 2; ++kk) {
            int rb = w * NW + n * 16 + l15;
            b_off[n][kk] = rb * 64 + (((kk * 4 + l16) ^ (rb & 7)) << 3);
        }

    int sg = (lane & 7) ^ ((lane >> 3) & 7);
    const short* ag = A  + (size_t)(row0 + w * 16 + (lane >> 3)) * K + sg * 8;
    const short* bg = Wt + (size_t)(col0 + w * NW + (lane >> 3)) * K + sg * 8;

    f32x4 acc[4][NF];
#pragma unroll
    for (int m = 0; m < 4; ++m)
#pragma unroll
        for (int n = 0; n < NF; ++n) acc[m][n] = (f32x4){0.f, 0.f, 0.f, 0.f};

    auto stage = [&](int buf, int kofs) {
#pragma unroll
        for (int c = 0; c < 2; ++c)
            GLL16(ag + (size_t)c * 8 * K + kofs, &As[buf][w * 1024 + c * 512]);
#pragma unroll
        for (int c = 0; c < BCH; ++c)
            GLL16(bg + (size_t)c * 8 * K + kofs, &Bs[buf][w * NW * 64 + c * 512]);
    };
    auto comp = [&](int buf) {
#pragma unroll
        for (int kk = 0; kk < 2; ++kk) {
            short8 af[4], bfr[NF];
#pragma unroll
            for (int m = 0; m < 4; ++m) af[m] = *(short8*)&As[buf][a_off[m][kk]];
#pragma unroll
            for (int n = 0; n < NF; ++n) bfr[n] = *(short8*)&Bs[buf][b_off[n][kk]];
#pragma unroll
            for (int m = 0; m < 4; ++m)
#pragma unroll
                for (int n = 0; n < NF; ++n)
                    acc[m][n] = __builtin_amdgcn_mfma_f32_16x16x32_bf16(af[m], bfr[n], acc[m][n], 0, 0, 0);
        }
    };

    // prologue: 2 stages in flight
    stage(0, 0);
    stage(1, 64);
    int ci = 0;
    for (int k0 = 128; k0 < K; k0 += 64) {
        stage((ci + 2) % 3, k0);          // issue 2 steps ahead
        waitcnt_vm<2 * LPW>();            // stage(ci) landed; 2 stages still in flight
        __builtin_amdgcn_s_barrier();     // all waves' stage(ci) visible
        comp(ci % 3);
        __builtin_amdgcn_s_barrier();     // reads done before buf reuse next iter
        ++ci;
    }
    waitcnt_vm<LPW>();
    __builtin_amdgcn_s_barrier();
    comp(ci % 3);
    waitcnt_vm<0>();
    __builtin_amdgcn_s_barrier();
    comp((ci + 1) % 3);

#pragma unroll
    for (int m = 0; m < 4; ++m) {
#pragma unroll
        for (int j = 0; j < 4; ++j) {
            int row = row0 + m * 16 + l16 * 4 + j;
#pragma unroll
            for (int n = 0; n < NF; ++n) {
                int col = col0 + w * NW + n * 16 + l15;
                float v = acc[m][n][j] + bias[col];
                if (act) v = 0.5f * v * (1.0f + erff(v * 0.70710678118654752f));
                if (resid) v += resid[(size_t)row * ldc + col];
                if (Cf) Cf[(size_t)row * ldc + col] = v;
                if (Cb) Cb[(size_t)row * ldc + col] =
                    f16out ? __builtin_bit_cast(short, (_Float16)v) : f2bf(v);
            }
        }
    }
}

template<int BN>
__global__ __launch_bounds__(256) void mm_kernel(
    const short* __restrict__ A, const short* __restrict__ Wt,
    const float* __restrict__ bias, const float* __restrict__ resid,
    float* __restrict__ Cf, short* __restrict__ Cb, int K, int ldc, int act)
{
    mm_body64<BN>(A, Wt, bias, resid, Cf, Cb, blockIdx.y * 64, blockIdx.x * BN, K, ldc, act, 0);
}

// two independent GEMMs (shared M, K): #1 -> f16 out (big), #2 -> bf16 out (val)
__global__ __launch_bounds__(256) void mm2_kernel(
    const short* __restrict__ A1, const short* __restrict__ Wt1, const float* __restrict__ bias1,
    short* __restrict__ C1, int ldc1,
    const short* __restrict__ A2, const short* __restrict__ Wt2, const float* __restrict__ bias2,
    short* __restrict__ C2, int ldc2,
    int nx1, int K)
{
    const short *A, *Wt; const float* bias; short* Cb; int ldc, col0, f16o;
    if ((int)blockIdx.x < nx1) {
        A = A1; Wt = Wt1; bias = bias1; Cb = C1; ldc = ldc1; f16o = 1;
        col0 = blockIdx.x * 128;
    } else {
        A = A2; Wt = Wt2; bias = bias2; Cb = C2; ldc = ldc2; f16o = 0;
        col0 = (blockIdx.x - nx1) * 128;
    }
    mm_body64<128>(A, Wt, bias, nullptr, nullptr, Cb, blockIdx.y * 64, col0, K, ldc, 0, f16o);
}

// ---------------- deformable sampling (f16 big staged in LDS, bf16 val, pk_fma) ----------------
__global__ __launch_bounds__(256) void sample_kernel(
    const short* __restrict__ big, const short* __restrict__ val, short* __restrict__ out)
{
    __shared__ float sw[8 * 132];
    __shared__ int   si[8 * 132];
    __shared__ _Float16 rowl[768];
    int bl = blockIdx.x;
    int b = bl / L_TOK, l = bl - b * L_TOK;
    const _Float16* row = (const _Float16*)big + (size_t)bl * 768;
    int t = threadIdx.x;
    if (t < 96) *(int4v*)&rowl[t * 8] = *(const int4v*)&row[t * 8];
    __syncthreads();
    {
        int head = t >> 5, lvp = t & 31, lv = lvp >> 3, p = lvp & 7;
        int lq, r;
        if (l < 4096)      { lq = 0; r = l;        }
        else if (l < 5120) { lq = 1; r = l - 4096; }
        else if (l < 5376) { lq = 2; r = l - 5120; }
        else               { lq = 3; r = l - 5376; }
        int sh = 6 - lq;
        float invSq = 1.0f / (float)(1 << sh);
        float refx = ((r & ((1 << sh) - 1)) + 0.5f) * invSq;
        float refy = ((r >> sh) + 0.5f) * invSq;
        int S = 64 >> lv;
        int start = (lv == 0) ? 0 : (lv == 1) ? 4096 : (lv == 2) ? 5120 : 5376;
        float Sf = (float)S;
        float logit = (float)rowl[512 + head * 32 + lvp];
        float mx = logit;
#pragma unroll
        for (int o = 16; o; o >>= 1) mx = fmaxf(mx, __shfl_xor(mx, o));
        float e = __expf(logit - mx);
        float ssum = e;
#pragma unroll
        for (int o = 16; o; o >>= 1) ssum += __shfl_xor(ssum, o);
        float a = e / ssum;
        float ox = (float)rowl[head * 64 + lv * 16 + p * 2 + 0];
        float oy = (float)rowl[head * 64 + lv * 16 + p * 2 + 1];
        float X = refx * Sf + ox - 0.5f;
        float Y = refy * Sf + oy - 0.5f;
        float x0 = floorf(X), y0 = floorf(Y);
        float fx = X - x0, fy = Y - y0;
        int xi0 = (int)x0, yi0 = (int)y0;
        int qt = lvp >> 3, sidx = lvp & 7;
        int base_w = head * 132 + qt * 33 + sidx * 4;
#pragma unroll
        for (int tap = 0; tap < 4; ++tap) {
            int dx = tap & 1, dy = tap >> 1;
            int xi = xi0 + dx, yi = yi0 + dy;
            float wgt = (dx ? fx : 1.0f - fx) * (dy ? fy : 1.0f - fy);
            bool valid = (xi >= 0) && (xi < S) && (yi >= 0) && (yi < S);
            int xc = xi < 0 ? 0 : (xi > S - 1 ? S - 1 : xi);
            int yc = yi < 0 ? 0 : (yi > S - 1 ? S - 1 : yi);
            sw[base_w + tap] = valid ? wgt * a : 0.0f;
            si[base_w + tap] = (start + yc * S + xc) << 8;   // pre-scaled by D=256
        }
    }
    __syncthreads();
    int h = t >> 5, sgp = (t >> 2) & 7, cg = t & 3;
    const short* vb = val + (size_t)b * L_TOK * D + h * 32 + cg * 8;
    v2f A0 = {0.f, 0.f}, A1 = {0.f, 0.f}, A2 = {0.f, 0.f}, A3 = {0.f, 0.f};
#pragma unroll
    for (int gp = 0; gp < 2; ++gp) {
        float w8[8]; int i8[8];
#pragma unroll
        for (int ss = 0; ss < 2; ++ss) {
            int base = h * 132 + (gp * 2 + ss) * 33 + sgp * 4;
#pragma unroll
            for (int tap = 0; tap < 4; ++tap) {
                w8[ss * 4 + tap] = sw[base + tap];
                i8[ss * 4 + tap] = si[base + tap];
            }
        }
        int4v gv[8];
#pragma unroll
        for (int k = 0; k < 8; ++k) gv[k] = *(const int4v*)&vb[i8[k]];
#pragma unroll
        for (int k = 0; k < 8; ++k) {
            v2f wp = {w8[k], w8[k]};
#pragma unroll
            for (int q = 0; q < 4; ++q) {
                unsigned dq = (unsigned)gv[k][q];
                v2f vv;
                vv[0] = __builtin_bit_cast(float, dq << 16);
                vv[1] = __builtin_bit_cast(float, dq & 0xffff0000u);
                if (q == 0) asm("v_pk_fma_f32 %0, %1, %2, %0" : "+v"(A0) : "v"(wp), "v"(vv));
                if (q == 1) asm("v_pk_fma_f32 %0, %1, %2, %0" : "+v"(A1) : "v"(wp), "v"(vv));
                if (q == 2) asm("v_pk_fma_f32 %0, %1, %2, %0" : "+v"(A2) : "v"(wp), "v"(vv));
                if (q == 3) asm("v_pk_fma_f32 %0, %1, %2, %0" : "+v"(A3) : "v"(wp), "v"(vv));
            }
        }
    }
    float r0 = A0[0], r1 = A0[1], r2 = A1[0], r3 = A1[1];
    float r4 = A2[0], r5 = A2[1], r6 = A3[0], r7 = A3[1];
#pragma unroll
    for (int o = 4; o <= 16; o <<= 1) {
        r0 += __shfl_xor(r0, o); r1 += __shfl_xor(r1, o);
        r2 += __shfl_xor(r2, o); r3 += __shfl_xor(r3, o);
        r4 += __shfl_xor(r4, o); r5 += __shfl_xor(r5, o);
        r6 += __shfl_xor(r6, o); r7 += __shfl_xor(r7, o);
    }
    if (sgp == 0) {
        short8 o;
        o[0] = f2bf(r0); o[1] = f2bf(r1); o[2] = f2bf(r2); o[3] = f2bf(r3);
        o[4] = f2bf(r4); o[5] = f2bf(r5); o[6] = f2bf(r6); o[7] = f2bf(r7);
        *(short8*)&out[(size_t)bl * D + h * 32 + cg * 8] = o;
    }
}

// ---------------- orchestration ----------------
extern "C" void kernel_launch(void* const* d_in, const int* in_sizes, int n_in,
                              void* d_out, int out_size, void* d_ws, size_t ws_size,
                              hipStream_t stream)
{
    const float* s0    = (const float*)d_in[0];
    const float* p0    = (const float*)d_in[1];
    const float* s1    = (const float*)d_in[2];
    const float* p1    = (const float*)d_in[3];
    const float* s2    = (const float*)d_in[4];
    const float* p2    = (const float*)d_in[5];
    const float* s3    = (const float*)d_in[6];
    const float* p3    = (const float*)d_in[7];
    const float* lvl   = (const float*)d_in[8];
    const float* W_off = (const float*)d_in[9];
    const float* b_off = (const float*)d_in[10];
    const float* W_att = (const float*)d_in[11];
    const float* b_att = (const float*)d_in[12];
    const float* W_val = (const float*)d_in[13];
    const float* b_val = (const float*)d_in[14];
    const float* W_out = (const float*)d_in[15];
    const float* b_out = (const float*)d_in[16];
    const float* ln1g  = (const float*)d_in[17];
    const float* ln1b  = (const float*)d_in[18];
    const float* W1    = (const float*)d_in[19];
    const float* b1    = (const float*)d_in[20];
    const float* W2    = (const float*)d_in[21];
    const float* b2    = (const float*)d_in[22];
    const float* ln2g  = (const float*)d_in[23];
    const float* ln2b  = (const float*)d_in[24];

    const size_t S1 = (size_t)NTOK * D;
    float* xbuf = (float*)d_ws;
    float* pos  = xbuf + S1;
    float* bigf = pos + S1;           // used as f16 (768 per token)
    float* bqa  = bigf + 3 * S1;
    short* big  = (short*)bigf;
    short* qbf   = (short*)(bqa + 6 * 768);
    short* x_bf  = qbf + S1;
    short* valbf = x_bf + S1;
    short* sampb = valbf + S1;
    short* hidbf = sampb + S1;
    short* wt_qa  = hidbf + 4 * S1;
    short* wt_val = wt_qa  + (size_t)6 * 768 * 256;
    short* wt_out = wt_val + (size_t)6 * 256 * 256;
    short* wt_1   = wt_out + (size_t)6 * 256 * 256;
    short* wt_2   = wt_1   + (size_t)6 * 1024 * 256;

    wconv_all<<<dim3(833, 1, 6), 256, 0, stream>>>(
        W_off, W_att, W_val, W_out, W1, W2, b_off, b_att,
        wt_qa, wt_val, wt_out, wt_1, wt_2, bqa);

    flat_all<<<2720, 256, 0, stream>>>(s0, p0, s1, p1, s2, p2, s3, p3, lvl, xbuf, x_bf, pos);

    for (int i = 0; i < 6; ++i) {
        ln_kernel<<<NTOK / 4, 256, 0, stream>>>(xbuf, ln1g + i * 256, ln1b + i * 256, pos, qbf);
        mm2_kernel<<<dim3(8, 170), 256, 0, stream>>>(
            qbf, wt_qa + (size_t)i * 768 * 256, bqa + i * 768, big, 768,
            x_bf, wt_val + (size_t)i * 256 * 256, b_val + i * 256, valbf, 256,
            6, 256);
        sample_kernel<<<NTOK, 256, 0, stream>>>(big, valbf, sampb);
        mm_kernel<64><<<dim3(4, 170), 256, 0, stream>>>(
            sampb, wt_out + (size_t)i * 256 * 256, b_out + i * 256, xbuf, xbuf, nullptr, 256, 256, 0);
        ln_kernel<<<NTOK / 4, 256, 0, stream>>>(xbuf, ln2g + i * 256, ln2b + i * 256, nullptr, qbf);
        mm_kernel<128><<<dim3(8, 170), 256, 0, stream>>>(
            qbf, wt_1 + (size_t)i * 1024 * 256, b1 + i * 1024, nullptr, nullptr, hidbf, 256, 1024, 1);
        float* outp = (i == 5) ? (float*)d_out : xbuf;
        short* xbp  = (i == 5) ? nullptr : x_bf;
        mm_kernel<64><<<dim3(4, 170), 256, 0, stream>>>(
            hidbf, wt_2 + (size_t)i * 256 * 1024, b2 + i * 256, xbuf, outp, xbp, 1024, 256, 0);
    }
}

// Round 16
// 759.661 us; speedup vs baseline: 1.0135x; 1.0135x over previous
//
#include <hip/hip_runtime.h>
#include <hip/hip_bf16.h>
#include <math.h>

#define L_TOK 5440
#define NTOK  10880   // B * L
#define D     256

typedef __attribute__((ext_vector_type(8))) short short8;
typedef __attribute__((ext_vector_type(4))) short short4v;
typedef __attribute__((ext_vector_type(4))) float f32x4;
typedef __attribute__((ext_vector_type(2))) float v2f;
typedef __attribute__((ext_vector_type(4))) int int4v;

__device__ __forceinline__ short f2bf(float f) {
    __hip_bfloat16 h = __float2bfloat16(f);
    return __builtin_bit_cast(short, h);
}
__device__ __forceinline__ float bf2f(short s) {
    unsigned u = ((unsigned)(unsigned short)s) << 16;
    return __builtin_bit_cast(float, u);
}

#define GLL16(gp, lp) \
    __builtin_amdgcn_global_load_lds((const __attribute__((address_space(1))) void*)(gp), \
                                     (__attribute__((address_space(3))) void*)(lp), 16, 0, 0)

// ---------------- flatten (single launch): (B,d,H,W) -> (B,L,d) f32 + bf16, pos += level_embed
__global__ __launch_bounds__(256) void flat_all(
    const float* __restrict__ s0, const float* __restrict__ p0,
    const float* __restrict__ s1, const float* __restrict__ p1,
    const float* __restrict__ s2, const float* __restrict__ p2,
    const float* __restrict__ s3, const float* __restrict__ p3,
    const float* __restrict__ le,
    float* __restrict__ x, short* __restrict__ xb, float* __restrict__ pos)
{
    __shared__ float ts[32][33], tp[32][33];
    int idx = blockIdx.x;
    const float *s, *p; int HW, start, lv, xt;
    if (idx < 2048)      {             s = s0; p = p0; HW = 4096; start = 0;    lv = 0; xt = 128; }
    else if (idx < 2560) { idx -= 2048; s = s1; p = p1; HW = 1024; start = 4096; lv = 1; xt = 32; }
    else if (idx < 2688) { idx -= 2560; s = s2; p = p2; HW = 256;  start = 5120; lv = 2; xt = 8; }
    else                 { idx -= 2688; s = s3; p = p3; HW = 64;   start = 5376; lv = 3; xt = 2; }
    int pix0 = (idx % xt) * 32;
    int rem  = idx / xt;
    int c0   = (rem & 7) * 32;
    int b    = rem >> 3;
    int tx = threadIdx.x & 31, ty = threadIdx.x >> 5;
#pragma unroll
    for (int i = 0; i < 4; ++i) {
        int c = c0 + ty + i * 8;
        size_t gi = ((size_t)b * D + c) * HW + pix0 + tx;
        ts[ty + i * 8][tx] = s[gi];
        tp[ty + i * 8][tx] = p[gi];
    }
    __syncthreads();
#pragma unroll
    for (int i = 0; i < 4; ++i) {
        int pix = pix0 + ty + i * 8;
        size_t bl = (size_t)b * L_TOK + start + pix;
        int c = c0 + tx;
        float v = ts[tx][ty + i * 8];
        x[bl * D + c]   = v;
        xb[bl * D + c]  = f2bf(v);
        pos[bl * D + c] = tp[tx][ty + i * 8] + le[lv * D + c];
    }
}

// ---------------- weight convert+transpose + bias pack, ALL in one launch ----------------
__global__ __launch_bounds__(256) void wconv_all(
    const float* __restrict__ Woff, const float* __restrict__ Watt,
    const float* __restrict__ Wval, const float* __restrict__ Wout,
    const float* __restrict__ W1,   const float* __restrict__ W2,
    const float* __restrict__ boff, const float* __restrict__ batt,
    short* __restrict__ wt_qa, short* __restrict__ wt_val, short* __restrict__ wt_out,
    short* __restrict__ wt_1,  short* __restrict__ wt_2, float* __restrict__ bqa)
{
    __shared__ float tile[32][33];
    int tidx = blockIdx.x, d = blockIdx.z;
    if (tidx == 832) {
        for (int c = threadIdx.x; c < 768; c += 256)
            bqa[d * 768 + c] = (c < 512) ? boff[d * 512 + c] : batt[d * 256 + c - 512];
        return;
    }
    const float* W; short* Wt; int K, N, dstride, rowoff, nx, t;
    if (tidx < 128)      { W = Woff; Wt = wt_qa;  K = 256;  N = 512;  dstride = 768 * 256;  rowoff = 0;   nx = 16; t = tidx; }
    else if (tidx < 192) { W = Watt; Wt = wt_qa;  K = 256;  N = 256;  dstride = 768 * 256;  rowoff = 512; nx = 8;  t = tidx - 128; }
    else if (tidx < 256) { W = Wval; Wt = wt_val; K = 256;  N = 256;  dstride = 256 * 256;  rowoff = 0;   nx = 8;  t = tidx - 192; }
    else if (tidx < 320) { W = Wout; Wt = wt_out; K = 256;  N = 256;  dstride = 256 * 256;  rowoff = 0;   nx = 8;  t = tidx - 256; }
    else if (tidx < 576) { W = W1;   Wt = wt_1;   K = 256;  N = 1024; dstride = 1024 * 256; rowoff = 0;   nx = 32; t = tidx - 320; }
    else                 { W = W2;   Wt = wt_2;   K = 1024; N = 256;  dstride = 256 * 1024; rowoff = 0;   nx = 8;  t = tidx - 576; }
    int n0 = (t % nx) * 32, k0 = (t / nx) * 32;
    const float* Wd = W + (size_t)d * K * N;
    short* Wtd = Wt + (size_t)d * dstride + (size_t)rowoff * K;
    int tx = threadIdx.x & 31, ty = threadIdx.x >> 5;
#pragma unroll
    for (int i = 0; i < 4; ++i)
        tile[ty + i * 8][tx] = Wd[(size_t)(k0 + ty + i * 8) * N + n0 + tx];
    __syncthreads();
#pragma unroll
    for (int i = 0; i < 4; ++i)
        Wtd[(size_t)(n0 + ty + i * 8) * K + k0 + tx] = f2bf(tile[tx][ty + i * 8]);
}

// ---------------- LayerNorm -> bf16 (one wave per token, float4 vectorized) ----------------
__global__ __launch_bounds__(256) void ln_kernel(
    const float* __restrict__ x, const float* __restrict__ g, const float* __restrict__ bta,
    const float* __restrict__ pos, short* __restrict__ out)
{
    int wid = threadIdx.x >> 6, lane = threadIdx.x & 63;
    int m = blockIdx.x * 4 + wid;
    int c4 = lane * 4;
    const float4 xv = *(const float4*)&x[(size_t)m * D + c4];
    float s = xv.x + xv.y + xv.z + xv.w;
#pragma unroll
    for (int o = 32; o; o >>= 1) s += __shfl_xor(s, o);
    float mean = s * (1.0f / D);
    float d0 = xv.x - mean, d1 = xv.y - mean, d2 = xv.z - mean, d3 = xv.w - mean;
    float sq = d0 * d0 + d1 * d1 + d2 * d2 + d3 * d3;
#pragma unroll
    for (int o = 32; o; o >>= 1) sq += __shfl_xor(sq, o);
    float rstd = rsqrtf(sq * (1.0f / D) + 1e-5f);
    const float4 gv = *(const float4*)&g[c4];
    const float4 bv = *(const float4*)&bta[c4];
    float o0 = d0 * rstd * gv.x + bv.x;
    float o1 = d1 * rstd * gv.y + bv.y;
    float o2 = d2 * rstd * gv.z + bv.z;
    float o3 = d3 * rstd * gv.w + bv.w;
    if (pos) {
        const float4 pv = *(const float4*)&pos[(size_t)m * D + c4];
        o0 += pv.x; o1 += pv.y; o2 += pv.z; o3 += pv.w;
    }
    short4v ov;
    ov[0] = f2bf(o0); ov[1] = f2bf(o1); ov[2] = f2bf(o2); ov[3] = f2bf(o3);
    *(short4v*)&out[(size_t)m * D + c4] = ov;
}

// ---------------- bf16 MFMA GEMM body (BM=64 x BN, BK=64, 4 waves, 2-phase dbuf) --------------
// r14 core (proven). vmode=1: bf16 output written head-major [b][h=col/32][L_TOK][32]
// (for the val projection consumed by sample's gathers — x-adjacent taps share a 128B line).
template<int BN>
__device__ __forceinline__ void mm_body64(
    const short* __restrict__ A, const short* __restrict__ Wt,
    const float* __restrict__ bias, const float* __restrict__ resid,
    float* __restrict__ Cf, short* __restrict__ Cb,
    int row0, int col0, int K, int ldc, int act, int f16out, int vmode)
{
    constexpr int NW  = BN / 4;
    constexpr int NF  = NW / 16;
    constexpr int BCH = BN / 32;
    __shared__ __align__(16) short As[2][64 * 64];
    __shared__ __align__(16) short Bs[2][BN * 64];
    int tid = threadIdx.x, lane = tid & 63, w = tid >> 6;
    int l15 = lane & 15, l16 = lane >> 4;

    int a_off[4][2], b_off[NF][2];
#pragma unroll
    for (int m = 0; m < 4; ++m)
#pragma unroll
        for (int kk = 0; kk < 2; ++kk) {
            int ra = m * 16 + l15;
            a_off[m][kk] = ra * 64 + (((kk * 4 + l16) ^ (ra & 7)) << 3);
        }
#pragma unroll
    for (int n = 0; n < NF; ++n)
#pragma unroll
        for (int kk = 0; kk < 2; ++kk) {
            int rb = w * NW + n * 16 + l15;
            b_off[n][kk] = rb * 64 + (((kk * 4 + l16) ^ (rb & 7)) << 3);
        }

    int sg = (lane & 7) ^ ((lane >> 3) & 7);
    const short* ag = A  + (size_t)(row0 + w * 16 + (lane >> 3)) * K + sg * 8;
    const short* bg = Wt + (size_t)(col0 + w * NW + (lane >> 3)) * K + sg * 8;

    f32x4 acc[4][NF];
#pragma unroll
    for (int m = 0; m < 4; ++m)
#pragma unroll
        for (int n = 0; n < NF; ++n) acc[m][n] = (f32x4){0.f, 0.f, 0.f, 0.f};

    auto stage = [&](int buf, int kofs) {
#pragma unroll
        for (int c = 0; c < 2; ++c)
            GLL16(ag + (size_t)c * 8 * K + kofs, &As[buf][w * 1024 + c * 512]);
#pragma unroll
        for (int c = 0; c < BCH; ++c)
            GLL16(bg + (size_t)c * 8 * K + kofs, &Bs[buf][w * NW * 64 + c * 512]);
    };
    auto comp = [&](int buf) {
#pragma unroll
        for (int kk = 0; kk < 2; ++kk) {
            short8 af[4], bfr[NF];
#pragma unroll
            for (int m = 0; m < 4; ++m) af[m] = *(short8*)&As[buf][a_off[m][kk]];
#pragma unroll
            for (int n = 0; n < NF; ++n) bfr[n] = *(short8*)&Bs[buf][b_off[n][kk]];
#pragma unroll
            for (int m = 0; m < 4; ++m)
#pragma unroll
                for (int n = 0; n < NF; ++n)
                    acc[m][n] = __builtin_amdgcn_mfma_f32_16x16x32_bf16(af[m], bfr[n], acc[m][n], 0, 0, 0);
        }
    };

    stage(0, 0);
    __syncthreads();
    int cur = 0;
    for (int k0 = 64; k0 < K; k0 += 64) {
        stage(cur ^ 1, k0);
        comp(cur);
        __syncthreads();
        cur ^= 1;
    }
    comp(cur);

    int bb = row0 >= L_TOK;          // block-uniform: 5440 % 64 == 0
#pragma unroll
    for (int m = 0; m < 4; ++m) {
#pragma unroll
        for (int j = 0; j < 4; ++j) {
            int row = row0 + m * 16 + l16 * 4 + j;
#pragma unroll
            for (int n = 0; n < NF; ++n) {
                int col = col0 + w * NW + n * 16 + l15;
                float v = acc[m][n][j] + bias[col];
                if (act) v = 0.5f * v * (1.0f + erff(v * 0.70710678118654752f));
                if (resid) v += resid[(size_t)row * ldc + col];
                if (Cf) Cf[(size_t)row * ldc + col] = v;
                if (Cb) {
                    if (vmode) {
                        size_t dst = (((size_t)bb * 8 + (col >> 5)) * L_TOK
                                      + (row - bb * L_TOK)) * 32 + (col & 31);
                        Cb[dst] = f2bf(v);
                    } else {
                        Cb[(size_t)row * ldc + col] =
                            f16out ? __builtin_bit_cast(short, (_Float16)v) : f2bf(v);
                    }
                }
            }
        }
    }
}

template<int BN>
__global__ __launch_bounds__(256) void mm_kernel(
    const short* __restrict__ A, const short* __restrict__ Wt,
    const float* __restrict__ bias, const float* __restrict__ resid,
    float* __restrict__ Cf, short* __restrict__ Cb, int K, int ldc, int act)
{
    mm_body64<BN>(A, Wt, bias, resid, Cf, Cb, blockIdx.y * 64, blockIdx.x * BN, K, ldc, act, 0, 0);
}

// two independent GEMMs (shared M, K): #1 -> f16 out (big), #2 -> bf16 head-major (val)
__global__ __launch_bounds__(256) void mm2_kernel(
    const short* __restrict__ A1, const short* __restrict__ Wt1, const float* __restrict__ bias1,
    short* __restrict__ C1, int ldc1,
    const short* __restrict__ A2, const short* __restrict__ Wt2, const float* __restrict__ bias2,
    short* __restrict__ C2, int ldc2,
    int nx1, int K)
{
    const short *A, *Wt; const float* bias; short* Cb; int ldc, col0, f16o, vmode;
    if ((int)blockIdx.x < nx1) {
        A = A1; Wt = Wt1; bias = bias1; Cb = C1; ldc = ldc1; f16o = 1; vmode = 0;
        col0 = blockIdx.x * 128;
    } else {
        A = A2; Wt = Wt2; bias = bias2; Cb = C2; ldc = ldc2; f16o = 0; vmode = 1;
        col0 = (blockIdx.x - nx1) * 128;
    }
    mm_body64<128>(A, Wt, bias, nullptr, nullptr, Cb, blockIdx.y * 64, col0, K, ldc, 0, f16o, vmode);
}

// ---------------- deformable sampling (f16 big staged in LDS, head-major bf16 val, pk_fma) -----
__global__ __launch_bounds__(256) void sample_kernel(
    const short* __restrict__ big, const short* __restrict__ val, short* __restrict__ out)
{
    __shared__ float sw[8 * 132];
    __shared__ int   si[8 * 132];
    __shared__ _Float16 rowl[768];
    int bl = blockIdx.x;
    int b = bl / L_TOK, l = bl - b * L_TOK;
    const _Float16* row = (const _Float16*)big + (size_t)bl * 768;
    int t = threadIdx.x;
    if (t < 96) *(int4v*)&rowl[t * 8] = *(const int4v*)&row[t * 8];
    __syncthreads();
    {
        int head = t >> 5, lvp = t & 31, lv = lvp >> 3, p = lvp & 7;
        int lq, r;
        if (l < 4096)      { lq = 0; r = l;        }
        else if (l < 5120) { lq = 1; r = l - 4096; }
        else if (l < 5376) { lq = 2; r = l - 5120; }
        else               { lq = 3; r = l - 5376; }
        int sh = 6 - lq;
        float invSq = 1.0f / (float)(1 << sh);
        float refx = ((r & ((1 << sh) - 1)) + 0.5f) * invSq;
        float refy = ((r >> sh) + 0.5f) * invSq;
        int S = 64 >> lv;
        int start = (lv == 0) ? 0 : (lv == 1) ? 4096 : (lv == 2) ? 5120 : 5376;
        float Sf = (float)S;
        float logit = (float)rowl[512 + head * 32 + lvp];
        float mx = logit;
#pragma unroll
        for (int o = 16; o; o >>= 1) mx = fmaxf(mx, __shfl_xor(mx, o));
        float e = __expf(logit - mx);
        float ssum = e;
#pragma unroll
        for (int o = 16; o; o >>= 1) ssum += __shfl_xor(ssum, o);
        float a = e / ssum;
        float ox = (float)rowl[head * 64 + lv * 16 + p * 2 + 0];
        float oy = (float)rowl[head * 64 + lv * 16 + p * 2 + 1];
        float X = refx * Sf + ox - 0.5f;
        float Y = refy * Sf + oy - 0.5f;
        float x0 = floorf(X), y0 = floorf(Y);
        float fx = X - x0, fy = Y - y0;
        int xi0 = (int)x0, yi0 = (int)y0;
        int qt = lvp >> 3, sidx = lvp & 7;
        int base_w = head * 132 + qt * 33 + sidx * 4;
#pragma unroll
        for (int tap = 0; tap < 4; ++tap) {
            int dx = tap & 1, dy = tap >> 1;
            int xi = xi0 + dx, yi = yi0 + dy;
            float wgt = (dx ? fx : 1.0f - fx) * (dy ? fy : 1.0f - fy);
            bool valid = (xi >= 0) && (xi < S) && (yi >= 0) && (yi < S);
            int xc = xi < 0 ? 0 : (xi > S - 1 ? S - 1 : xi);
            int yc = yi < 0 ? 0 : (yi > S - 1 ? S - 1 : yi);
            sw[base_w + tap] = valid ? wgt * a : 0.0f;
            si[base_w + tap] = (start + yc * S + xc) << 5;   // head-major: *32 shorts
        }
    }
    __syncthreads();
    int h = t >> 5, sgp = (t >> 2) & 7, cg = t & 3;
    // head-major val: [b][h][L_TOK][32]
    const short* vb = val + ((size_t)(b * 8 + h) * L_TOK) * 32 + cg * 8;
    v2f A0 = {0.f, 0.f}, A1 = {0.f, 0.f}, A2 = {0.f, 0.f}, A3 = {0.f, 0.f};
#pragma unroll
    for (int gp = 0; gp < 2; ++gp) {
        float w8[8]; int i8[8];
#pragma unroll
        for (int ss = 0; ss < 2; ++ss) {
            int base = h * 132 + (gp * 2 + ss) * 33 + sgp * 4;
#pragma unroll
            for (int tap = 0; tap < 4; ++tap) {
                w8[ss * 4 + tap] = sw[base + tap];
                i8[ss * 4 + tap] = si[base + tap];
            }
        }
        int4v gv[8];
#pragma unroll
        for (int k = 0; k < 8; ++k) gv[k] = *(const int4v*)&vb[i8[k]];
#pragma unroll
        for (int k = 0; k < 8; ++k) {
            v2f wp = {w8[k], w8[k]};
#pragma unroll
            for (int q = 0; q < 4; ++q) {
                unsigned dq = (unsigned)gv[k][q];
                v2f vv;
                vv[0] = __builtin_bit_cast(float, dq << 16);
                vv[1] = __builtin_bit_cast(float, dq & 0xffff0000u);
                if (q == 0) asm("v_pk_fma_f32 %0, %1, %2, %0" : "+v"(A0) : "v"(wp), "v"(vv));
                if (q == 1) asm("v_pk_fma_f32 %0, %1, %2, %0" : "+v"(A1) : "v"(wp), "v"(vv));
                if (q == 2) asm("v_pk_fma_f32 %0, %1, %2, %0" : "+v"(A2) : "v"(wp), "v"(vv));
                if (q == 3) asm("v_pk_fma_f32 %0, %1, %2, %0" : "+v"(A3) : "v"(wp), "v"(vv));
            }
        }
    }
    float r0 = A0[0], r1 = A0[1], r2 = A1[0], r3 = A1[1];
    float r4 = A2[0], r5 = A2[1], r6 = A3[0], r7 = A3[1];
#pragma unroll
    for (int o = 4; o <= 16; o <<= 1) {
        r0 += __shfl_xor(r0, o); r1 += __shfl_xor(r1, o);
        r2 += __shfl_xor(r2, o); r3 += __shfl_xor(r3, o);
        r4 += __shfl_xor(r4, o); r5 += __shfl_xor(r5, o);
        r6 += __shfl_xor(r6, o); r7 += __shfl_xor(r7, o);
    }
    if (sgp == 0) {
        short8 o;
        o[0] = f2bf(r0); o[1] = f2bf(r1); o[2] = f2bf(r2); o[3] = f2bf(r3);
        o[4] = f2bf(r4); o[5] = f2bf(r5); o[6] = f2bf(r6); o[7] = f2bf(r7);
        *(short8*)&out[(size_t)bl * D + h * 32 + cg * 8] = o;
    }
}

// ---------------- orchestration ----------------
extern "C" void kernel_launch(void* const* d_in, const int* in_sizes, int n_in,
                              void* d_out, int out_size, void* d_ws, size_t ws_size,
                              hipStream_t stream)
{
    const float* s0    = (const float*)d_in[0];
    const float* p0    = (const float*)d_in[1];
    const float* s1    = (const float*)d_in[2];
    const float* p1    = (const float*)d_in[3];
    const float* s2    = (const float*)d_in[4];
    const float* p2    = (const float*)d_in[5];
    const float* s3    = (const float*)d_in[6];
    const float* p3    = (const float*)d_in[7];
    const float* lvl   = (const float*)d_in[8];
    const float* W_off = (const float*)d_in[9];
    const float* b_off = (const float*)d_in[10];
    const float* W_att = (const float*)d_in[11];
    const float* b_att = (const float*)d_in[12];
    const float* W_val = (const float*)d_in[13];
    const float* b_val = (const float*)d_in[14];
    const float* W_out = (const float*)d_in[15];
    const float* b_out = (const float*)d_in[16];
    const float* ln1g  = (const float*)d_in[17];
    const float* ln1b  = (const float*)d_in[18];
    const float* W1    = (const float*)d_in[19];
    const float* b1    = (const float*)d_in[20];
    const float* W2    = (const float*)d_in[21];
    const float* b2    = (const float*)d_in[22];
    const float* ln2g  = (const float*)d_in[23];
    const float* ln2b  = (const float*)d_in[24];

    const size_t S1 = (size_t)NTOK * D;
    float* xbuf = (float*)d_ws;
    float* pos  = xbuf + S1;
    float* bigf = pos + S1;           // used as f16 (768 per token)
    float* bqa  = bigf + 3 * S1;
    short* big  = (short*)bigf;
    short* qbf   = (short*)(bqa + 6 * 768);
    short* x_bf  = qbf + S1;
    short* valbf = x_bf + S1;         // head-major [b][h][L][32]
    short* sampb = valbf + S1;
    short* hidbf = sampb + S1;
    short* wt_qa  = hidbf + 4 * S1;
    short* wt_val = wt_qa  + (size_t)6 * 768 * 256;
    short* wt_out = wt_val + (size_t)6 * 256 * 256;
    short* wt_1   = wt_out + (size_t)6 * 256 * 256;
    short* wt_2   = wt_1   + (size_t)6 * 1024 * 256;

    wconv_all<<<dim3(833, 1, 6), 256, 0, stream>>>(
        W_off, W_att, W_val, W_out, W1, W2, b_off, b_att,
        wt_qa, wt_val, wt_out, wt_1, wt_2, bqa);

    flat_all<<<2720, 256, 0, stream>>>(s0, p0, s1, p1, s2, p2, s3, p3, lvl, xbuf, x_bf, pos);

    for (int i = 0; i < 6; ++i) {
        ln_kernel<<<NTOK / 4, 256, 0, stream>>>(xbuf, ln1g + i * 256, ln1b + i * 256, pos, qbf);
        mm2_kernel<<<dim3(8, 170), 256, 0, stream>>>(
            qbf, wt_qa + (size_t)i * 768 * 256, bqa + i * 768, big, 768,
            x_bf, wt_val + (size_t)i * 256 * 256, b_val + i * 256, valbf, 256,
            6, 256);
        sample_kernel<<<NTOK, 256, 0, stream>>>(big, valbf, sampb);
        mm_kernel<64><<<dim3(4, 170), 256, 0, stream>>>(
            sampb, wt_out + (size_t)i * 256 * 256, b_out + i * 256, xbuf, xbuf, nullptr, 256, 256, 0);
        ln_kernel<<<NTOK / 4, 256, 0, stream>>>(xbuf, ln2g + i * 256, ln2b + i * 256, nullptr, qbf);
        mm_kernel<128><<<dim3(8, 170), 256, 0, stream>>>(
            qbf, wt_1 + (size_t)i * 1024 * 256, b1 + i * 1024, nullptr, nullptr, hidbf, 256, 1024, 1);
        float* outp = (i == 5) ? (float*)d_out : xbuf;
        short* xbp  = (i == 5) ? nullptr : x_bf;
        mm_kernel<64><<<dim3(4, 170), 256, 0, stream>>>(
            hidbf, wt_2 + (size_t)i * 256 * 1024, b2 + i * 256, xbuf, outp, xbp, 1024, 256, 0);
    }
}

// Round 17
// 745.833 us; speedup vs baseline: 1.0323x; 1.0185x over previous
//
#include <hip/hip_runtime.h>
#include <hip/hip_bf16.h>
#include <math.h>

#define L_TOK 5440
#define NTOK  10880   // B * L
#define D     256

typedef __attribute__((ext_vector_type(8))) short short8;
typedef __attribute__((ext_vector_type(4))) short short4v;
typedef __attribute__((ext_vector_type(4))) float f32x4;
typedef __attribute__((ext_vector_type(2))) float v2f;
typedef __attribute__((ext_vector_type(4))) int int4v;

__device__ __forceinline__ short f2bf(float f) {
    __hip_bfloat16 h = __float2bfloat16(f);
    return __builtin_bit_cast(short, h);
}
__device__ __forceinline__ float bf2f(short s) {
    unsigned u = ((unsigned)(unsigned short)s) << 16;
    return __builtin_bit_cast(float, u);
}

#define GLL16(gp, lp) \
    __builtin_amdgcn_global_load_lds((const __attribute__((address_space(1))) void*)(gp), \
                                     (__attribute__((address_space(3))) void*)(lp), 16, 0, 0)

// ---------------- flatten (single launch): (B,d,H,W) -> (B,L,d) f32 + bf16, pos += level_embed
__global__ __launch_bounds__(256) void flat_all(
    const float* __restrict__ s0, const float* __restrict__ p0,
    const float* __restrict__ s1, const float* __restrict__ p1,
    const float* __restrict__ s2, const float* __restrict__ p2,
    const float* __restrict__ s3, const float* __restrict__ p3,
    const float* __restrict__ le,
    float* __restrict__ x, short* __restrict__ xb, float* __restrict__ pos)
{
    __shared__ float ts[32][33], tp[32][33];
    int idx = blockIdx.x;
    const float *s, *p; int HW, start, lv, xt;
    if (idx < 2048)      {             s = s0; p = p0; HW = 4096; start = 0;    lv = 0; xt = 128; }
    else if (idx < 2560) { idx -= 2048; s = s1; p = p1; HW = 1024; start = 4096; lv = 1; xt = 32; }
    else if (idx < 2688) { idx -= 2560; s = s2; p = p2; HW = 256;  start = 5120; lv = 2; xt = 8; }
    else                 { idx -= 2688; s = s3; p = p3; HW = 64;   start = 5376; lv = 3; xt = 2; }
    int pix0 = (idx % xt) * 32;
    int rem  = idx / xt;
    int c0   = (rem & 7) * 32;
    int b    = rem >> 3;
    int tx = threadIdx.x & 31, ty = threadIdx.x >> 5;
#pragma unroll
    for (int i = 0; i < 4; ++i) {
        int c = c0 + ty + i * 8;
        size_t gi = ((size_t)b * D + c) * HW + pix0 + tx;
        ts[ty + i * 8][tx] = s[gi];
        tp[ty + i * 8][tx] = p[gi];
    }
    __syncthreads();
#pragma unroll
    for (int i = 0; i < 4; ++i) {
        int pix = pix0 + ty + i * 8;
        size_t bl = (size_t)b * L_TOK + start + pix;
        int c = c0 + tx;
        float v = ts[tx][ty + i * 8];
        x[bl * D + c]   = v;
        xb[bl * D + c]  = f2bf(v);
        pos[bl * D + c] = tp[tx][ty + i * 8] + le[lv * D + c];
    }
}

// ---------------- weight convert+transpose + bias pack, ALL in one launch ----------------
__global__ __launch_bounds__(256) void wconv_all(
    const float* __restrict__ Woff, const float* __restrict__ Watt,
    const float* __restrict__ Wval, const float* __restrict__ Wout,
    const float* __restrict__ W1,   const float* __restrict__ W2,
    const float* __restrict__ boff, const float* __restrict__ batt,
    short* __restrict__ wt_qa, short* __restrict__ wt_val, short* __restrict__ wt_out,
    short* __restrict__ wt_1,  short* __restrict__ wt_2, float* __restrict__ bqa)
{
    __shared__ float tile[32][33];
    int tidx = blockIdx.x, d = blockIdx.z;
    if (tidx == 832) {
        for (int c = threadIdx.x; c < 768; c += 256)
            bqa[d * 768 + c] = (c < 512) ? boff[d * 512 + c] : batt[d * 256 + c - 512];
        return;
    }
    const float* W; short* Wt; int K, N, dstride, rowoff, nx, t;
    if (tidx < 128)      { W = Woff; Wt = wt_qa;  K = 256;  N = 512;  dstride = 768 * 256;  rowoff = 0;   nx = 16; t = tidx; }
    else if (tidx < 192) { W = Watt; Wt = wt_qa;  K = 256;  N = 256;  dstride = 768 * 256;  rowoff = 512; nx = 8;  t = tidx - 128; }
    else if (tidx < 256) { W = Wval; Wt = wt_val; K = 256;  N = 256;  dstride = 256 * 256;  rowoff = 0;   nx = 8;  t = tidx - 192; }
    else if (tidx < 320) { W = Wout; Wt = wt_out; K = 256;  N = 256;  dstride = 256 * 256;  rowoff = 0;   nx = 8;  t = tidx - 256; }
    else if (tidx < 576) { W = W1;   Wt = wt_1;   K = 256;  N = 1024; dstride = 1024 * 256; rowoff = 0;   nx = 32; t = tidx - 320; }
    else                 { W = W2;   Wt = wt_2;   K = 1024; N = 256;  dstride = 256 * 1024; rowoff = 0;   nx = 8;  t = tidx - 576; }
    int n0 = (t % nx) * 32, k0 = (t / nx) * 32;
    const float* Wd = W + (size_t)d * K * N;
    short* Wtd = Wt + (size_t)d * dstride + (size_t)rowoff * K;
    int tx = threadIdx.x & 31, ty = threadIdx.x >> 5;
#pragma unroll
    for (int i = 0; i < 4; ++i)
        tile[ty + i * 8][tx] = Wd[(size_t)(k0 + ty + i * 8) * N + n0 + tx];
    __syncthreads();
#pragma unroll
    for (int i = 0; i < 4; ++i)
        Wtd[(size_t)(n0 + ty + i * 8) * K + k0 + tx] = f2bf(tile[tx][ty + i * 8]);
}

// ---------------- LayerNorm -> bf16 (one wave per token, float4 vectorized) ----------------
__global__ __launch_bounds__(256) void ln_kernel(
    const float* __restrict__ x, const float* __restrict__ g, const float* __restrict__ bta,
    const float* __restrict__ pos, short* __restrict__ out)
{
    int wid = threadIdx.x >> 6, lane = threadIdx.x & 63;
    int m = blockIdx.x * 4 + wid;
    int c4 = lane * 4;
    const float4 xv = *(const float4*)&x[(size_t)m * D + c4];
    float s = xv.x + xv.y + xv.z + xv.w;
#pragma unroll
    for (int o = 32; o; o >>= 1) s += __shfl_xor(s, o);
    float mean = s * (1.0f / D);
    float d0 = xv.x - mean, d1 = xv.y - mean, d2 = xv.z - mean, d3 = xv.w - mean;
    float sq = d0 * d0 + d1 * d1 + d2 * d2 + d3 * d3;
#pragma unroll
    for (int o = 32; o; o >>= 1) sq += __shfl_xor(sq, o);
    float rstd = rsqrtf(sq * (1.0f / D) + 1e-5f);
    const float4 gv = *(const float4*)&g[c4];
    const float4 bv = *(const float4*)&bta[c4];
    float o0 = d0 * rstd * gv.x + bv.x;
    float o1 = d1 * rstd * gv.y + bv.y;
    float o2 = d2 * rstd * gv.z + bv.z;
    float o3 = d3 * rstd * gv.w + bv.w;
    if (pos) {
        const float4 pv = *(const float4*)&pos[(size_t)m * D + c4];
        o0 += pv.x; o1 += pv.y; o2 += pv.z; o3 += pv.w;
    }
    short4v ov;
    ov[0] = f2bf(o0); ov[1] = f2bf(o1); ov[2] = f2bf(o2); ov[3] = f2bf(o3);
    *(short4v*)&out[(size_t)m * D + c4] = ov;
}

// ---------------- bf16 MFMA GEMM body (BM=64 x BN, BK=64, 4 waves, 2-phase dbuf) --------------
template<int BN>
__device__ __forceinline__ void mm_body64(
    const short* __restrict__ A, const short* __restrict__ Wt,
    const float* __restrict__ bias, const float* __restrict__ resid,
    float* __restrict__ Cf, short* __restrict__ Cb,
    int row0, int col0, int K, int ldc, int act, int f16out)
{
    constexpr int NW  = BN / 4;
    constexpr int NF  = NW / 16;
    constexpr int BCH = BN / 32;
    __shared__ __align__(16) short As[2][64 * 64];
    __shared__ __align__(16) short Bs[2][BN * 64];
    int tid = threadIdx.x, lane = tid & 63, w = tid >> 6;
    int l15 = lane & 15, l16 = lane >> 4;

    int a_off[4][2], b_off[NF][2];
#pragma unroll
    for (int m = 0; m < 4; ++m)
#pragma unroll
        for (int kk = 0; kk < 2; ++kk) {
            int ra = m * 16 + l15;
            a_off[m][kk] = ra * 64 + (((kk * 4 + l16) ^ (ra & 7)) << 3);
        }
#pragma unroll
    for (int n = 0; n < NF; ++n)
#pragma unroll
        for (int kk = 0; kk < 2; ++kk) {
            int rb = w * NW + n * 16 + l15;
            b_off[n][kk] = rb * 64 + (((kk * 4 + l16) ^ (rb & 7)) << 3);
        }

    int sg = (lane & 7) ^ ((lane >> 3) & 7);
    const short* ag = A  + (size_t)(row0 + w * 16 + (lane >> 3)) * K + sg * 8;
    const short* bg = Wt + (size_t)(col0 + w * NW + (lane >> 3)) * K + sg * 8;

    f32x4 acc[4][NF];
#pragma unroll
    for (int m = 0; m < 4; ++m)
#pragma unroll
        for (int n = 0; n < NF; ++n) acc[m][n] = (f32x4){0.f, 0.f, 0.f, 0.f};

    auto stage = [&](int buf, int kofs) {
#pragma unroll
        for (int c = 0; c < 2; ++c)
            GLL16(ag + (size_t)c * 8 * K + kofs, &As[buf][w * 1024 + c * 512]);
#pragma unroll
        for (int c = 0; c < BCH; ++c)
            GLL16(bg + (size_t)c * 8 * K + kofs, &Bs[buf][w * NW * 64 + c * 512]);
    };
    auto comp = [&](int buf) {
#pragma unroll
        for (int kk = 0; kk < 2; ++kk) {
            short8 af[4], bfr[NF];
#pragma unroll
            for (int m = 0; m < 4; ++m) af[m] = *(short8*)&As[buf][a_off[m][kk]];
#pragma unroll
            for (int n = 0; n < NF; ++n) bfr[n] = *(short8*)&Bs[buf][b_off[n][kk]];
#pragma unroll
            for (int m = 0; m < 4; ++m)
#pragma unroll
                for (int n = 0; n < NF; ++n)
                    acc[m][n] = __builtin_amdgcn_mfma_f32_16x16x32_bf16(af[m], bfr[n], acc[m][n], 0, 0, 0);
        }
    };

    stage(0, 0);
    __syncthreads();
    int cur = 0;
    for (int k0 = 64; k0 < K; k0 += 64) {
        stage(cur ^ 1, k0);
        comp(cur);
        __syncthreads();
        cur ^= 1;
    }
    comp(cur);

#pragma unroll
    for (int m = 0; m < 4; ++m) {
#pragma unroll
        for (int j = 0; j < 4; ++j) {
            int row = row0 + m * 16 + l16 * 4 + j;
#pragma unroll
            for (int n = 0; n < NF; ++n) {
                int col = col0 + w * NW + n * 16 + l15;
                float v = acc[m][n][j] + bias[col];
                if (act) v = 0.5f * v * (1.0f + erff(v * 0.70710678118654752f));
                if (resid) v += resid[(size_t)row * ldc + col];
                if (Cf) Cf[(size_t)row * ldc + col] = v;
                if (Cb) Cb[(size_t)row * ldc + col] =
                    f16out ? __builtin_bit_cast(short, (_Float16)v) : f2bf(v);
            }
        }
    }
}

template<int BN>
__global__ __launch_bounds__(256) void mm_kernel(
    const short* __restrict__ A, const short* __restrict__ Wt,
    const float* __restrict__ bias, const float* __restrict__ resid,
    float* __restrict__ Cf, short* __restrict__ Cb, int K, int ldc, int act)
{
    mm_body64<BN>(A, Wt, bias, resid, Cf, Cb, blockIdx.y * 64, blockIdx.x * BN, K, ldc, act, 0);
}

// two independent GEMMs (shared M, K): #1 -> f16 out (big), #2 -> bf16 out (val)
__global__ __launch_bounds__(256) void mm2_kernel(
    const short* __restrict__ A1, const short* __restrict__ Wt1, const float* __restrict__ bias1,
    short* __restrict__ C1, int ldc1,
    const short* __restrict__ A2, const short* __restrict__ Wt2, const float* __restrict__ bias2,
    short* __restrict__ C2, int ldc2,
    int nx1, int K)
{
    const short *A, *Wt; const float* bias; short* Cb; int ldc, col0, f16o;
    if ((int)blockIdx.x < nx1) {
        A = A1; Wt = Wt1; bias = bias1; Cb = C1; ldc = ldc1; f16o = 1;
        col0 = blockIdx.x * 128;
    } else {
        A = A2; Wt = Wt2; bias = bias2; Cb = C2; ldc = ldc2; f16o = 0;
        col0 = (blockIdx.x - nx1) * 128;
    }
    mm_body64<128>(A, Wt, bias, nullptr, nullptr, Cb, blockIdx.y * 64, col0, K, ldc, 0, f16o);
}

// ---------------- deformable sampling (f16 big staged in LDS, bf16 val, pk_fma) ----------------
__global__ __launch_bounds__(256) void sample_kernel(
    const short* __restrict__ big, const short* __restrict__ val, short* __restrict__ out)
{
    __shared__ float sw[8 * 132];
    __shared__ int   si[8 * 132];
    __shared__ _Float16 rowl[768];
    int bl = blockIdx.x;
    int b = bl / L_TOK, l = bl - b * L_TOK;
    const _Float16* row = (const _Float16*)big + (size_t)bl * 768;
    int t = threadIdx.x;
    if (t < 96) *(int4v*)&rowl[t * 8] = *(const int4v*)&row[t * 8];
    __syncthreads();
    {
        int head = t >> 5, lvp = t & 31, lv = lvp >> 3, p = lvp & 7;
        int lq, r;
        if (l < 4096)      { lq = 0; r = l;        }
        else if (l < 5120) { lq = 1; r = l - 4096; }
        else if (l < 5376) { lq = 2; r = l - 5120; }
        else               { lq = 3; r = l - 5376; }
        int sh = 6 - lq;
        float invSq = 1.0f / (float)(1 << sh);
        float refx = ((r & ((1 << sh) - 1)) + 0.5f) * invSq;
        float refy = ((r >> sh) + 0.5f) * invSq;
        int S = 64 >> lv;
        int start = (lv == 0) ? 0 : (lv == 1) ? 4096 : (lv == 2) ? 5120 : 5376;
        float Sf = (float)S;
        float logit = (float)rowl[512 + head * 32 + lvp];
        float mx = logit;
#pragma unroll
        for (int o = 16; o; o >>= 1) mx = fmaxf(mx, __shfl_xor(mx, o));
        float e = __expf(logit - mx);
        float ssum = e;
#pragma unroll
        for (int o = 16; o; o >>= 1) ssum += __shfl_xor(ssum, o);
        float a = e / ssum;
        float ox = (float)rowl[head * 64 + lv * 16 + p * 2 + 0];
        float oy = (float)rowl[head * 64 + lv * 16 + p * 2 + 1];
        float X = refx * Sf + ox - 0.5f;
        float Y = refy * Sf + oy - 0.5f;
        float x0 = floorf(X), y0 = floorf(Y);
        float fx = X - x0, fy = Y - y0;
        int xi0 = (int)x0, yi0 = (int)y0;
        int qt = lvp >> 3, sidx = lvp & 7;
        int base_w = head * 132 + qt * 33 + sidx * 4;
#pragma unroll
        for (int tap = 0; tap < 4; ++tap) {
            int dx = tap & 1, dy = tap >> 1;
            int xi = xi0 + dx, yi = yi0 + dy;
            float wgt = (dx ? fx : 1.0f - fx) * (dy ? fy : 1.0f - fy);
            bool valid = (xi >= 0) && (xi < S) && (yi >= 0) && (yi < S);
            int xc = xi < 0 ? 0 : (xi > S - 1 ? S - 1 : xi);
            int yc = yi < 0 ? 0 : (yi > S - 1 ? S - 1 : yi);
            sw[base_w + tap] = valid ? wgt * a : 0.0f;
            si[base_w + tap] = (start + yc * S + xc) << 8;   // pre-scaled by D=256
        }
    }
    __syncthreads();
    int h = t >> 5, sgp = (t >> 2) & 7, cg = t & 3;
    const short* vb = val + (size_t)b * L_TOK * D + h * 32 + cg * 8;
    v2f A0 = {0.f, 0.f}, A1 = {0.f, 0.f}, A2 = {0.f, 0.f}, A3 = {0.f, 0.f};
#pragma unroll
    for (int gp = 0; gp < 2; ++gp) {
        float w8[8]; int i8[8];
#pragma unroll
        for (int ss = 0; ss < 2; ++ss) {
            int base = h * 132 + (gp * 2 + ss) * 33 + sgp * 4;
#pragma unroll
            for (int tap = 0; tap < 4; ++tap) {
                w8[ss * 4 + tap] = sw[base + tap];
                i8[ss * 4 + tap] = si[base + tap];
            }
        }
        int4v gv[8];
#pragma unroll
        for (int k = 0; k < 8; ++k) gv[k] = *(const int4v*)&vb[i8[k]];
#pragma unroll
        for (int k = 0; k < 8; ++k) {
            v2f wp = {w8[k], w8[k]};
#pragma unroll
            for (int q = 0; q < 4; ++q) {
                unsigned dq = (unsigned)gv[k][q];
                v2f vv;
                vv[0] = __builtin_bit_cast(float, dq << 16);
                vv[1] = __builtin_bit_cast(float, dq & 0xffff0000u);
                if (q == 0) asm("v_pk_fma_f32 %0, %1, %2, %0" : "+v"(A0) : "v"(wp), "v"(vv));
                if (q == 1) asm("v_pk_fma_f32 %0, %1, %2, %0" : "+v"(A1) : "v"(wp), "v"(vv));
                if (q == 2) asm("v_pk_fma_f32 %0, %1, %2, %0" : "+v"(A2) : "v"(wp), "v"(vv));
                if (q == 3) asm("v_pk_fma_f32 %0, %1, %2, %0" : "+v"(A3) : "v"(wp), "v"(vv));
            }
        }
    }
    float r0 = A0[0], r1 = A0[1], r2 = A1[0], r3 = A1[1];
    float r4 = A2[0], r5 = A2[1], r6 = A3[0], r7 = A3[1];
#pragma unroll
    for (int o = 4; o <= 16; o <<= 1) {
        r0 += __shfl_xor(r0, o); r1 += __shfl_xor(r1, o);
        r2 += __shfl_xor(r2, o); r3 += __shfl_xor(r3, o);
        r4 += __shfl_xor(r4, o); r5 += __shfl_xor(r5, o);
        r6 += __shfl_xor(r6, o); r7 += __shfl_xor(r7, o);
    }
    if (sgp == 0) {
        short8 o;
        o[0] = f2bf(r0); o[1] = f2bf(r1); o[2] = f2bf(r2); o[3] = f2bf(r3);
        o[4] = f2bf(r4); o[5] = f2bf(r5); o[6] = f2bf(r6); o[7] = f2bf(r7);
        *(short8*)&out[(size_t)bl * D + h * 32 + cg * 8] = o;
    }
}

// ---------------- orchestration ----------------
extern "C" void kernel_launch(void* const* d_in, const int* in_sizes, int n_in,
                              void* d_out, int out_size, void* d_ws, size_t ws_size,
                              hipStream_t stream)
{
    const float* s0    = (const float*)d_in[0];
    const float* p0    = (const float*)d_in[1];
    const float* s1    = (const float*)d_in[2];
    const float* p1    = (const float*)d_in[3];
    const float* s2    = (const float*)d_in[4];
    const float* p2    = (const float*)d_in[5];
    const float* s3    = (const float*)d_in[6];
    const float* p3    = (const float*)d_in[7];
    const float* lvl   = (const float*)d_in[8];
    const float* W_off = (const float*)d_in[9];
    const float* b_off = (const float*)d_in[10];
    const float* W_att = (const float*)d_in[11];
    const float* b_att = (const float*)d_in[12];
    const float* W_val = (const float*)d_in[13];
    const float* b_val = (const float*)d_in[14];
    const float* W_out = (const float*)d_in[15];
    const float* b_out = (const float*)d_in[16];
    const float* ln1g  = (const float*)d_in[17];
    const float* ln1b  = (const float*)d_in[18];
    const float* W1    = (const float*)d_in[19];
    const float* b1    = (const float*)d_in[20];
    const float* W2    = (const float*)d_in[21];
    const float* b2    = (const float*)d_in[22];
    const float* ln2g  = (const float*)d_in[23];
    const float* ln2b  = (const float*)d_in[24];

    const size_t S1 = (size_t)NTOK * D;
    float* xbuf = (float*)d_ws;
    float* pos  = xbuf + S1;
    float* bigf = pos + S1;           // used as f16 (768 per token)
    float* bqa  = bigf + 3 * S1;
    short* big  = (short*)bigf;
    short* qbf   = (short*)(bqa + 6 * 768);
    short* x_bf  = qbf + S1;
    short* valbf = x_bf + S1;
    short* sampb = valbf + S1;
    short* hidbf = sampb + S1;
    short* wt_qa  = hidbf + 4 * S1;
    short* wt_val = wt_qa  + (size_t)6 * 768 * 256;
    short* wt_out = wt_val + (size_t)6 * 256 * 256;
    short* wt_1   = wt_out + (size_t)6 * 256 * 256;
    short* wt_2   = wt_1   + (size_t)6 * 1024 * 256;

    wconv_all<<<dim3(833, 1, 6), 256, 0, stream>>>(
        W_off, W_att, W_val, W_out, W1, W2, b_off, b_att,
        wt_qa, wt_val, wt_out, wt_1, wt_2, bqa);

    flat_all<<<2720, 256, 0, stream>>>(s0, p0, s1, p1, s2, p2, s3, p3, lvl, xbuf, x_bf, pos);

    for (int i = 0; i < 6; ++i) {
        ln_kernel<<<NTOK / 4, 256, 0, stream>>>(xbuf, ln1g + i * 256, ln1b + i * 256, pos, qbf);
        mm2_kernel<<<dim3(8, 170), 256, 0, stream>>>(
            qbf, wt_qa + (size_t)i * 768 * 256, bqa + i * 768, big, 768,
            x_bf, wt_val + (size_t)i * 256 * 256, b_val + i * 256, valbf, 256,
            6, 256);
        sample_kernel<<<NTOK, 256, 0, stream>>>(big, valbf, sampb);
        mm_kernel<64><<<dim3(4, 170), 256, 0, stream>>>(
            sampb, wt_out + (size_t)i * 256 * 256, b_out + i * 256, xbuf, xbuf, nullptr, 256, 256, 0);
        ln_kernel<<<NTOK / 4, 256, 0, stream>>>(xbuf, ln2g + i * 256, ln2b + i * 256, nullptr, qbf);
        mm_kernel<128><<<dim3(8, 170), 256, 0, stream>>>(
            qbf, wt_1 + (size_t)i * 1024 * 256, b1 + i * 1024, nullptr, nullptr, hidbf, 256, 1024, 1);
        float* outp = (i == 5) ? (float*)d_out : xbuf;
        short* xbp  = (i == 5) ? nullptr : x_bf;
        mm_kernel<64><<<dim3(4, 170), 256, 0, stream>>>(
            hidbf, wt_2 + (size_t)i * 256 * 1024, b2 + i * 256, xbuf, outp, xbp, 1024, 256, 0);
    }
}